// Round 11
// baseline (175.718 us; speedup 1.0000x reference)
//
#include <hip/hip_runtime.h>

#define B_ 4
#define C_ 256
#define N_ 4096

typedef unsigned short u16;
typedef unsigned char u8;
typedef __bf16 bf16x8 __attribute__((ext_vector_type(8)));
typedef float f32x4 __attribute__((ext_vector_type(4)));
typedef float f32x16 __attribute__((ext_vector_type(16)));
typedef u16 u16x8 __attribute__((ext_vector_type(8)));
typedef u16 u16x4 __attribute__((ext_vector_type(4)));
typedef u8 u8x16 __attribute__((ext_vector_type(16)));

union BF8 { u16x8 u; bf16x8 b; };

__device__ __forceinline__ u16 f2bf(float f) {  // RNE
  unsigned int u = __float_as_uint(f);
  u += 0x7fffu + ((u >> 16) & 1u);
  return (u16)(u >> 16);
}
__device__ __forceinline__ u16 f2bf_fast(float f) {  // round-half-up
  return (u16)((__float_as_uint(f) + 0x8000u) >> 16);
}
__device__ __forceinline__ float bf2f(u16 u) {
  return __uint_as_float(((unsigned int)u) << 16);
}

__device__ __forceinline__ f32x16 mfma32(bf16x8 a, bf16x8 b, f32x16 c) {
  return __builtin_amdgcn_mfma_f32_32x32x16_bf16(a, b, c, 0, 0, 0);
}
__device__ __forceinline__ f32x16 mfma32f8(long a, long b, f32x16 c) {
  return __builtin_amdgcn_mfma_f32_32x32x16_fp8_fp8(a, b, c, 0, 0, 0);
}

// async global->LDS, 16B/lane, dest = wave-uniform base + lane*16
__device__ __forceinline__ void gl_lds16(const u8* g, u8* l) {
  __builtin_amdgcn_global_load_lds(
      (const __attribute__((address_space(1))) unsigned int*)g,
      (__attribute__((address_space(3))) unsigned int*)l, 16, 0, 0);
}

#define ROWMAP(r, half) (((r) & 3) + 8 * ((r) >> 2) + 4 * (half))

// sqrt((1/16)*log2e): folded into BOTH q and k -> softmax is bare exp2,
// and fp8 values sit in e4m3 normal range.
#define QK_SCALE 0.30028063f

// ---------------- weights fp32 -> bf16 (once, tiny) ----------------
__global__ __launch_bounds__(256) void k_prep(const float* __restrict__ wq,
                                              const float* __restrict__ wo,
                                              u16* __restrict__ Wqb,
                                              u16* __restrict__ Wob) {
  int i = blockIdx.x * 256 + threadIdx.x;  // 65536 float4 chunks
  const int QCH = (3 * C_ * C_) / 4;
  const float* src = (i < QCH) ? wq + (size_t)i * 4 : wo + (size_t)(i - QCH) * 4;
  u16* dst = (i < QCH) ? Wqb + (size_t)i * 4 : Wob + (size_t)(i - QCH) * 4;
  f32x4 v = *(const f32x4*)src;
  u16x4 r = {f2bf(v[0]), f2bf(v[1]), f2bf(v[2]), f2bf(v[3])};
  *(u16x4*)dst = r;
}

// ---------------- QKV projection -> fp8 Q/K/V ----------------
// Staging: 4-lane groups load 4 c-rows x float4, 4x4 transpose via
// shfl_xor(1/2) (DPP quad-perm), pack u16x4 -> one b64 LDS write per it
// (replaces 64 scalar ~8x-conflicted ds_write_b16 per thread).
__global__ __launch_bounds__(256, 2) void k_qkv(
    const u16* __restrict__ Wqb, const float* __restrict__ bias,
    const float* __restrict__ x, u8* __restrict__ Qt, u8* __restrict__ Kt,
    u8* __restrict__ Vn) {
  __shared__ u16 Xs[64 * 264];
  __shared__ u8 Sg[9216];  // SQ: [64 pix][136] or SV: [128 c][72]
  const int b = blockIdx.z, yb = blockIdx.y, n0 = blockIdx.x * 64;
  const int t = threadIdx.x, w = t >> 6, lane = t & 63;
  const int l32 = lane & 31, half = lane >> 5;
  const int g4 = t >> 2, j4 = t & 3;
#pragma unroll
  for (int it = 0; it < 16; ++it) {
    int T = it * 64 + g4;      // tile id
    int c0 = (T >> 4) * 4;     // c-tile base (0..252)
    int nl = (T & 15) * 4;     // n-local base (0..60)
    f32x4 v =
        *(const f32x4*)(x + ((size_t)b * C_ + c0 + j4) * N_ + n0 + nl);
    // 4x4 transpose across lanes j4=0..3
    {
      bool o1 = j4 & 1;
      float s0 = o1 ? v[0] : v[1];
      float s1 = o1 ? v[2] : v[3];
      s0 = __shfl_xor(s0, 1);
      s1 = __shfl_xor(s1, 1);
      if (o1) { v[0] = s0; v[2] = s1; } else { v[1] = s0; v[3] = s1; }
      bool o2 = j4 & 2;
      s0 = o2 ? v[0] : v[2];
      s1 = o2 ? v[1] : v[3];
      s0 = __shfl_xor(s0, 2);
      s1 = __shfl_xor(s1, 2);
      if (o2) { v[0] = s0; v[1] = s1; } else { v[2] = s0; v[3] = s1; }
    }
    // lane j4 now holds n = nl+j4, c = c0..c0+3
    u16x4 pkv = {f2bf(v[0]), f2bf(v[1]), f2bf(v[2]), f2bf(v[3])};
    *(u16x4*)&Xs[(nl + j4) * 264 + c0] = pkv;
  }
  __syncthreads();

  BF8 xf[2][16];
#pragma unroll
  for (int nt = 0; nt < 2; ++nt)
#pragma unroll
    for (int ks = 0; ks < 16; ++ks)
      xf[nt][ks].u =
          *(const u16x8*)&Xs[(nt * 32 + l32) * 264 + ks * 16 + half * 8];

#pragma unroll
  for (int mt = 0; mt < 3; ++mt) {
    const int omr = yb * 384 + mt * 128;  // 128-wide tile, uniform seg
    const int seg = omr >> 8;             // 0=Q 1=K 2=V
    const int ow = omr + w * 32;          // this wave's 32 outputs
    BF8 wf[16];
    const u16* wrow = Wqb + (size_t)(ow + l32) * C_ + half * 8;
#pragma unroll
    for (int ks = 0; ks < 16; ++ks) wf[ks].u = *(const u16x8*)(wrow + ks * 16);

    f32x16 a0, a1;
#pragma unroll
    for (int r = 0; r < 16; ++r) a0[r] = a1[r] = 0.f;

    if (seg < 2) {
      // A = wf (m=o), B = xf (n=pix): regs -> o = ow+ROWMAP, lane -> pix
#pragma unroll
      for (int ks = 0; ks < 16; ++ks) {
        a0 = mfma32(wf[ks].b, xf[0][ks].b, a0);
        a1 = mfma32(wf[ks].b, xf[1][ks].b, a1);
      }
#pragma unroll
      for (int nt = 0; nt < 2; ++nt) {
        const f32x16& a = nt ? a1 : a0;
#pragma unroll
        for (int g = 0; g < 4; ++g) {
          f32x4 bv = *(const f32x4*)&bias[ow + 8 * g + 4 * half];
          float v0 = (a[4 * g + 0] + bv[0]) * QK_SCALE;
          float v1 = (a[4 * g + 1] + bv[1]) * QK_SCALE;
          float v2 = (a[4 * g + 2] + bv[2]) * QK_SCALE;
          float v3 = (a[4 * g + 3] + bv[3]) * QK_SCALE;
          int pkw = __builtin_amdgcn_cvt_pk_fp8_f32(v0, v1, 0, false);
          pkw = __builtin_amdgcn_cvt_pk_fp8_f32(v2, v3, pkw, true);
          *(int*)&Sg[(nt * 32 + l32) * 136 + w * 32 + 8 * g + 4 * half] = pkw;
        }
      }
      __syncthreads();
      {  // full-128B-line stores: Qt/Kt[b][pix][ol..ol+128)
        u8* dst = ((seg == 0) ? Qt : Kt) + ((size_t)b * N_ + n0) * C_ +
                  (omr & 255);
        int row = t >> 2, cb = t & 3;
        u8x16 q0 = *(const u8x16*)&Sg[row * 136 + cb * 32];
        u8x16 q1 = *(const u8x16*)&Sg[row * 136 + cb * 32 + 16];
        u8* d = dst + (size_t)row * C_ + cb * 32;
        *(u8x16*)d = q0;
        *(u8x16*)(d + 16) = q1;
      }
      __syncthreads();
    } else {
      // A = xf (m=pix), B = wf (n=c): regs -> pix = ROWMAP, lane -> c
#pragma unroll
      for (int ks = 0; ks < 16; ++ks) {
        a0 = mfma32(xf[0][ks].b, wf[ks].b, a0);
        a1 = mfma32(xf[1][ks].b, wf[ks].b, a1);
      }
      const float bvv = bias[ow + l32];
#pragma unroll
      for (int nt = 0; nt < 2; ++nt) {
        const f32x16& a = nt ? a1 : a0;
#pragma unroll
        for (int g = 0; g < 4; ++g) {
          float v0 = a[4 * g + 0] + bvv, v1 = a[4 * g + 1] + bvv;
          float v2 = a[4 * g + 2] + bvv, v3 = a[4 * g + 3] + bvv;
          int pkw = __builtin_amdgcn_cvt_pk_fp8_f32(v0, v1, 0, false);
          pkw = __builtin_amdgcn_cvt_pk_fp8_f32(v2, v3, pkw, true);
          *(int*)&Sg[(w * 32 + l32) * 72 + nt * 32 + 8 * g + 4 * half] = pkw;
        }
      }
      __syncthreads();
      {  // Vn[b][c][n0..n0+64): 64B sectors
        u8* dst = Vn + ((size_t)b * C_ + (omr - 512)) * N_ + n0;
        int row = t >> 1, ch = t & 1;
        u8x16 q0 = *(const u8x16*)&Sg[row * 72 + ch * 32];
        u8x16 q1 = *(const u8x16*)&Sg[row * 72 + ch * 32 + 16];
        u8* d = dst + (size_t)row * N_ + ch * 32;
        *(u8x16*)d = q0;
        *(u8x16*)(d + 16) = q1;
      }
      __syncthreads();
    }
  }
}

// ---------------- out-proj + split-combine + bias + residual ----------------
__global__ __launch_bounds__(256, 2) void k_out(
    const u16* __restrict__ Wob, const float* __restrict__ bias,
    const float* __restrict__ xres, float* __restrict__ outp,
    const u16* __restrict__ Op, const float* __restrict__ Ml) {
  __shared__ u16 Xs[32 * 264];
  const int b = blockIdx.y, n0 = blockIdx.x * 32;
  const int t = threadIdx.x, w = t >> 6, lane = t & 63;
  const int l32 = lane & 31, half = lane >> 5;
  const size_t TEN = (size_t)B_ * N_ * C_;
  const size_t BN = (size_t)B_ * N_;
#pragma unroll
  for (int it = 0; it < 4; ++it) {
    int chunk = t + 256 * it;
    int row = chunk >> 5, col = chunk & 31;
    size_t rowg = (size_t)b * N_ + n0 + row;
    float f = 1.0f / (Ml[rowg] + Ml[BN + rowg] + Ml[2 * BN + rowg] +
                      Ml[3 * BN + rowg]);
    size_t base = rowg * C_ + col * 8;
    u16x8 a0 = *(const u16x8*)&Op[base];
    u16x8 a1 = *(const u16x8*)&Op[TEN + base];
    u16x8 rr;
#pragma unroll
    for (int i = 0; i < 8; ++i) rr[i] = f2bf((bf2f(a0[i]) + bf2f(a1[i])) * f);
    *(u16x8*)&Xs[row * 264 + col * 8] = rr;
  }
  __syncthreads();

  BF8 xf[16];
#pragma unroll
  for (int ks = 0; ks < 16; ++ks)
    xf[ks].u = *(const u16x8*)&Xs[l32 * 264 + ks * 16 + half * 8];

#pragma unroll
  for (int mt = 0; mt < 2; ++mt) {
    const int om = w * 64 + mt * 32;
    BF8 wf[16];
    const u16* wrow = Wob + (size_t)(om + l32) * C_ + half * 8;
#pragma unroll
    for (int ks = 0; ks < 16; ++ks) wf[ks].u = *(const u16x8*)(wrow + ks * 16);
    f32x16 a;
#pragma unroll
    for (int r = 0; r < 16; ++r) a[r] = 0.f;
#pragma unroll
    for (int ks = 0; ks < 16; ++ks) a = mfma32(wf[ks].b, xf[ks].b, a);
#pragma unroll
    for (int r = 0; r < 16; ++r) {
      int oc = om + ROWMAP(r, half);
      size_t idx = ((size_t)b * C_ + oc) * N_ + n0 + l32;
      outp[idx] = a[r] + bias[oc] + xres[idx];
    }
  }
}

// ---------------- flash attention: fp8 MFMA, global_load_lds staging --------
// K LDS layout: 16 groups of 4 rows, group stride 1040 B (4x256+16 pad) ->
// kf b64 reads hit exactly 4 dw/bank (wave64 minimum, verified by hand).
// Granule swizzle g^(row&15) unchanged. V: 256 rows x 64 B (conflict-free).
// raw: K[2] @ 0/16640, V[2] @ 33280/49664; epilogue reuses as M[2][64][264].
__global__ __launch_bounds__(256, 2) void k_attn(const u8* __restrict__ Qt,
                                                 const u8* __restrict__ Kt,
                                                 const u8* __restrict__ Vn,
                                                 u16* __restrict__ Op,
                                                 float* __restrict__ Ml) {
  __shared__ u8 raw[67584];
  const int id = blockIdx.x;
  const int xcd = id & 7;
  const int b = xcd >> 1;
  const int jh = xcd & 1;
  const int i0 = (id >> 3) * 64;
  const int t = threadIdx.x, w = t >> 6, lane = t & 63;
  const int l32 = lane & 31, half = lane >> 5;
  const int mh = w >> 1, jh2 = w & 1;

  long qf[16];
  {
    const u8* qrow = Qt + ((size_t)b * N_ + i0 + mh * 32 + l32) * C_ + half * 8;
#pragma unroll
    for (int ks = 0; ks < 16; ++ks) qf[ks] = *(const long*)(qrow + ks * 16);
  }
  f32x16 o[8];
#pragma unroll
  for (int ct = 0; ct < 8; ++ct)
#pragma unroll
    for (int r = 0; r < 16; ++r) o[ct][r] = 0.f;
  float l_i = 0.f;

  const u8* kbase = Kt + (size_t)b * N_ * C_;
  const u8* vbase = Vn + (size_t)b * (size_t)C_ * N_;
  const int jbeg = jh * (N_ / 2), jend = jbeg + N_ / 2;

  const int kR = lane >> 4, kG = lane & 15;  // K: 4 rows/call, granule
  const int vR = lane >> 2, vG = lane & 3;   // V: 16 rows/call, granule

  auto stage = [&](int j0, int buf) {
#pragma unroll
    for (int it = 0; it < 4; ++it) {
      int r0 = w * 16 + it * 4;  // group base row (group = w*4+it)
      const u8* g =
          kbase + (size_t)(j0 + r0 + kR) * C_ + ((kG ^ ((r0 + kR) & 15)) << 4);
      gl_lds16(g, raw + buf * 16640 + (w * 4 + it) * 1040);
    }
#pragma unroll
    for (int it = 0; it < 4; ++it) {
      int cloc = w * 64 + it * 16 + vR;  // 0..255
      const u8* g =
          vbase + (size_t)cloc * N_ + j0 + ((vG ^ ((cloc >> 1) & 3)) << 4);
      gl_lds16(g, raw + 33280 + buf * 16384 + (w * 64 + it * 16) * 64);
    }
  };

  stage(jbeg, 0);
  __syncthreads();
  int cur = 0;

  for (int j0 = jbeg; j0 < jend; j0 += 64) {
    int jn = j0 + 64;
    if (jn >= jend) jn = jbeg;  // last iter: dummy (valid) prefetch
    stage(jn, cur ^ 1);

    // S^T 32x32: lane = q-row l32, regs = j-local = 8g+4half+i
    f32x16 s;
#pragma unroll
    for (int r = 0; r < 16; ++r) s[r] = 0.f;
    {
      const int jrow = jh2 * 32 + l32;
      const u8* krowp = raw + cur * 16640 + (jrow >> 2) * 1040 +
                        (jrow & 3) * 256 + half * 8;
#pragma unroll
      for (int ks = 0; ks < 16; ++ks) {
        long kf = *(const long*)(krowp + ((ks ^ (jrow & 15)) << 4));
        s = mfma32f8(kf, qf[ks], s);
      }
    }

    // p = exp2(s) -> fp8 dwords pd[g] (bytes i <-> j = 8g+4half+i)
    int pd[4];
    float tile_sum = 0.f;
#pragma unroll
    for (int g = 0; g < 4; ++g) {
      float p0 = exp2f(s[4 * g + 0]), p1 = exp2f(s[4 * g + 1]);
      float p2 = exp2f(s[4 * g + 2]), p3 = exp2f(s[4 * g + 3]);
      tile_sum += (p0 + p1) + (p2 + p3);
      int w0 = __builtin_amdgcn_cvt_pk_fp8_f32(p0, p1, 0, false);
      pd[g] = __builtin_amdgcn_cvt_pk_fp8_f32(p2, p3, w0, true);
    }
    tile_sum += __shfl_xor(tile_sum, 32);
    l_i += tile_sum;

    // B-frag for PV chunk kc: bytes <-> j = 16kc + 8half + {0..7};
    // own dword pd[2kc+half] + partner's (lane^32) give the two halves.
    long pb[2];
#pragma unroll
    for (int kc = 0; kc < 2; ++kc) {
      int own = pd[2 * kc + half];
      int oth = __shfl_xor(pd[2 * kc + (half ^ 1)], 32);
      unsigned lo = half ? (unsigned)oth : (unsigned)own;
      unsigned hi = half ? (unsigned)own : (unsigned)oth;
      pb[kc] = (long)(((unsigned long long)hi << 32) | lo);
    }

    // O^T += V^T P^T: A = Vs[c][j] frag, B = pb; D lane = q-row, regs = c
    {
      const u8* vbp = raw + 33280 + cur * 16384;
      const int sw = (l32 >> 1) & 3;
#pragma unroll
      for (int ct = 0; ct < 8; ++ct) {
        const u8* vrowp = vbp + (ct * 32 + l32) * 64 + half * 8;
#pragma unroll
        for (int kc = 0; kc < 2; ++kc) {
          long vf = *(const long*)(vrowp + (((2 * jh2 + kc) ^ sw) << 4));
          o[ct] = mfma32f8(vf, pb[kc], o[ct]);
        }
      }
    }

    __syncthreads();  // drains global_load_lds (vmcnt) + LDS reads done
    cur ^= 1;
  }

  // ---- merge jh2 partials via LDS (reuses raw), coalesced Op store
  float* ml = Ml + ((size_t)(jh * 2 + jh2) * B_ + b) * N_;
  if (lane < 32) ml[i0 + mh * 32 + l32] = l_i;

  u16* M = (u16*)raw;  // [2][64][264]
#pragma unroll
  for (int ct = 0; ct < 8; ++ct)
#pragma unroll
    for (int g = 0; g < 4; ++g) {
      u16x4 pkv = {f2bf_fast(o[ct][4 * g + 0]), f2bf_fast(o[ct][4 * g + 1]),
                   f2bf_fast(o[ct][4 * g + 2]), f2bf_fast(o[ct][4 * g + 3])};
      *(u16x4*)&M[jh2 * (64 * 264) + (mh * 32 + l32) * 264 + ct * 32 + 8 * g +
                  4 * half] = pkv;
    }
  __syncthreads();

  u16* op = Op + ((size_t)jh * B_ + b) * (size_t)N_ * C_ + (size_t)i0 * C_;
  const int row = t >> 2, cb = t & 3;
#pragma unroll
  for (int k = 0; k < 8; ++k) {
    u16x8 m0 = *(const u16x8*)&M[row * 264 + cb * 64 + k * 8];
    u16x8 m1 = *(const u16x8*)&M[64 * 264 + row * 264 + cb * 64 + k * 8];
    u16x8 rr;
#pragma unroll
    for (int i = 0; i < 8; ++i) rr[i] = f2bf_fast(bf2f(m0[i]) + bf2f(m1[i]));
    *(u16x8*)&op[(size_t)row * C_ + cb * 64 + k * 8] = rr;
  }
}

extern "C" void kernel_launch(void* const* d_in, const int* in_sizes, int n_in,
                              void* d_out, int out_size, void* d_ws,
                              size_t ws_size, hipStream_t stream) {
  (void)in_sizes; (void)n_in; (void)out_size; (void)ws_size;
  const float* x = (const float*)d_in[0];
  const float* w_qkv = (const float*)d_in[1];
  const float* b_qkv = (const float*)d_in[2];
  const float* w_out = (const float*)d_in[3];
  const float* b_out = (const float*)d_in[4];
  float* outp = (float*)d_out;

  const size_t TENS = (size_t)B_ * N_ * C_;  // 4M elems
  u8* Qt = (u8*)d_ws;        // [B][N][C] fp8 (scaled)      4 MB
  u8* Kt = Qt + TENS;        // [B][N][C] fp8 (scaled)      4 MB
  u8* Vn = Kt + TENS;        // [B][C][N] fp8               4 MB
  u16* Op = (u16*)(Vn + TENS);  // [2][B][N][C] bf16       16 MB
  float* Ml = (float*)(Op + 2 * TENS);          // [4][B][N]  256 KB
  u16* Wqb = (u16*)(Ml + 4 * (size_t)B_ * N_);  // [3C][C]    384 KB
  u16* Wob = Wqb + 3 * C_ * C_;                 // [C][C]     128 KB

  k_prep<<<dim3(256), 256, 0, stream>>>(w_qkv, w_out, Wqb, Wob);
  k_qkv<<<dim3(64, 2, 4), 256, 0, stream>>>(Wqb, b_qkv, x, Qt, Kt, Vn);
  k_attn<<<dim3(512), 256, 0, stream>>>(Qt, Kt, Vn, Op, Ml);
  k_out<<<dim3(128, 4), 256, 0, stream>>>(Wob, b_out, x, outp, Op, Ml);
}